// Round 4
// baseline (133.498 us; speedup 1.0000x reference)
//
#include <hip/hip_runtime.h>
#include <hip/hip_cooperative_groups.h>
#include <float.h>

namespace cg = cooperative_groups;

#define BB 4
#define NN 2048
#define SS 256
#define FF 7680   // C_FEAT * NA = 128*60
#define PP 24
#define TF 120    // f-rows per block in phase C (64 tiles * 4 batches = 256 blocks)
#define GRID 256
#define TPN 8
#define NPB 32    // n's per block in phase A
#define CHUNKS 64 // NN / NPB
#define SPT 32    // SS / TPN
#define PPT 3     // PP / TPN
#define LDS_BYTES (TF * SS * 4)  // 122880

#define KVPAD(s) ((s) + ((s) >> 5))

// ws layout (floats): [0,128) invd[b][p], [128,128+BB*SS*PP) A_T[b][s][p],
// then partial[256][SS][PP], then dsumP[256][PP]

// branchless insert of (v, vi) into ascending triple, strict < (incumbent wins ties)
#define INSERT3(v, vi)                                                       \
    {                                                                        \
        bool c0 = (v) < t0, c1 = (v) < t1, c2 = (v) < t2;                    \
        float n2 = c1 ? t1 : (c2 ? (v) : t2);                                \
        int m2 = c1 ? j1 : (c2 ? (vi) : j2);                                 \
        float n1 = c0 ? t0 : (c1 ? (v) : t1);                                \
        int m1 = c0 ? j0 : (c1 ? (vi) : j1);                                 \
        t0 = c0 ? (v) : t0;                                                  \
        j0 = c0 ? (vi) : j0;                                                 \
        t1 = n1; j1 = m1; t2 = n2; j2 = m2;                                  \
    }

// merge partner's triple; lower-s-range thread's triple is the base (wins ties)
#define MERGE_ROUND(m)                                                       \
    {                                                                        \
        float q0 = __shfl_xor(t0, (m)), q1 = __shfl_xor(t1, (m)),            \
              q2 = __shfl_xor(t2, (m));                                      \
        int r0 = __shfl_xor(j0, (m)), r1 = __shfl_xor(j1, (m)),              \
            r2 = __shfl_xor(j2, (m));                                        \
        bool lw = ((h & (m)) == 0);                                          \
        float is0 = lw ? q0 : t0, is1 = lw ? q1 : t1, is2 = lw ? q2 : t2;    \
        int ij0 = lw ? r0 : j0, ij1 = lw ? r1 : j1, ij2 = lw ? r2 : j2;      \
        float bs0 = lw ? t0 : q0, bs1 = lw ? t1 : q1, bs2 = lw ? t2 : q2;    \
        int bj0 = lw ? j0 : r0, bj1 = lw ? j1 : r1, bj2 = lw ? j2 : r2;      \
        t0 = bs0; t1 = bs1; t2 = bs2; j0 = bj0; j1 = bj1; j2 = bj2;          \
        INSERT3(is0, ij0);                                                   \
        INSERT3(is1, ij1);                                                   \
        INSERT3(is2, ij2);                                                   \
    }

template <bool USE_PARTIAL>
__global__ __launch_bounds__(256, 1) void fused(
    const float* __restrict__ xyz1, const float* __restrict__ xyz2,
    const float* __restrict__ pts2, const float* __restrict__ ps,
    float* __restrict__ ws, float* __restrict__ out) {
    extern __shared__ __align__(16) char smem[];
    cg::grid_group grid = cg::this_grid();
    const int tid = threadIdx.x;
    const int blk = blockIdx.x;

    float* invd = ws;
    float* aT = ws + 128;
    float* partial = aT + BB * SS * PP;
    float* dsumP = partial + (size_t)GRID * SS * PP;

    if (!USE_PARTIAL) {  // fallback: zero aT + denom, then atomic-accumulate
        int i = blk * 256 + tid;
        if (i < 128 + BB * SS * PP) ws[i] = 0.f;
        grid.sync();
    }

    // ---------------- phase A: 3-NN + scatter into per-block partial ----------------
    {
        float4* kv = (float4*)smem;                       // 264 float4
        float* aloc = (float*)(smem + 4352);              // [SS][PP]
        float* dsum = (float*)(smem + 4352 + SS * PP * 4);
        int b = blk >> 6;
        int chunk = blk & 63;
        {
            int s = tid;
            float x = xyz2[b * 3 * SS + s];
            float y = xyz2[b * 3 * SS + SS + s];
            float z = xyz2[b * 3 * SS + 2 * SS + s];
            kv[KVPAD(s)] = make_float4(x, y, z, x * x + y * y + z * z);
        }
        for (int i = tid; i < SS * PP; i += 256) aloc[i] = 0.f;
        if (tid < PP) dsum[tid] = 0.f;
        __syncthreads();

        int h = tid % TPN;
        int n = chunk * NPB + tid / TPN;
        const float* x1p = xyz1 + ((size_t)b * NN + n) * 3;
        float x = x1p[0], y = x1p[1], z = x1p[2];
        float x1sq = x * x + y * y + z * z;

        float t0 = FLT_MAX, t1 = FLT_MAX, t2 = FLT_MAX;
        int j0 = 0, j1 = 0, j2 = 0;
        int sbeg = h * SPT;
#pragma unroll 4
        for (int s = sbeg; s < sbeg + SPT; ++s) {
            float4 c = kv[KVPAD(s)];
            float dt = x * c.x;
            dt = fmaf(y, c.y, dt);
            dt = fmaf(z, c.z, dt);
            float d = fmaf(-2.f, dt, x1sq + c.w);
            INSERT3(d, s);
        }
#pragma unroll
        for (int m = 1; m < TPN; m <<= 1) { MERGE_ROUND(m); }

        float w0 = 1.f / (t0 + 1e-8f);
        float w1 = 1.f / (t1 + 1e-8f);
        float w2 = 1.f / (t2 + 1e-8f);
        float wsum = w0 + w1 + w2;
        w0 /= wsum; w1 /= wsum; w2 /= wsum;

        const float* prow = ps + ((size_t)b * NN + n) * PP + h * PPT;
#pragma unroll
        for (int j = 0; j < PPT; ++j) {
            float v = prow[j];
            atomicAdd(&dsum[h * PPT + j], fabsf(v));
            atomicAdd(&aloc[j0 * PP + h * PPT + j], v * w0);
            atomicAdd(&aloc[j1 * PP + h * PPT + j], v * w1);
            atomicAdd(&aloc[j2 * PP + h * PPT + j], v * w2);
        }
        __syncthreads();

        if (USE_PARTIAL) {
            float* d2 = partial + (size_t)blk * (SS * PP);
            for (int i = tid; i < SS * PP; i += 256) d2[i] = aloc[i];
            if (tid < PP) dsumP[blk * PP + tid] = dsum[tid];
        } else {
            float* d2 = aT + (size_t)b * (SS * PP);
            for (int i = tid; i < SS * PP; i += 256) unsafeAtomicAdd(&d2[i], aloc[i]);
            if (tid < PP) unsafeAtomicAdd(&invd[b * PP + tid], dsum[tid]);
        }
    }
    grid.sync();

    // ---------------- phase B: reduce partials -> A_T, invd ----------------
    if (USE_PARTIAL) {
        int idx = blk * 256 + tid;
        if (idx < BB * SS * PP) {
            int b2 = idx / (SS * PP);
            int sp = idx - b2 * (SS * PP);
            const float* srcp = partial + (size_t)b2 * CHUNKS * (SS * PP) + sp;
            float acc = 0.f;
#pragma unroll 4
            for (int c = 0; c < CHUNKS; ++c) acc += srcp[(size_t)c * (SS * PP)];
            aT[idx] = acc;
        }
        if (blk == 0 && tid < BB * PP) {
            int b2 = tid / PP, p = tid - b2 * PP;
            float s = 0.f;
#pragma unroll 4
            for (int c = 0; c < CHUNKS; ++c) s += dsumP[((size_t)b2 * CHUNKS + c) * PP + p];
            invd[tid] = 1.f / fmaxf(s, 1e-12f);
        }
    } else {
        if (blk == 0 && tid < BB * PP) invd[tid] = 1.f / fmaxf(invd[tid], 1e-12f);
    }
    grid.sync();

    // ---------------- phase C: out[b,p,f] = invd[b,p] * sum_s A_T[b,s,p]*X[b,f,s] ----------------
    {
        int b = blk >> 6;
        int tile = blk & 63;
        int fbase = tile * TF;
        float4* xs4 = (float4*)smem;  // [TF][64] float4, col-swizzled

        const float4* src = (const float4*)(pts2 + ((size_t)b * FF + fbase) * SS);
        for (int t = tid; t < TF * 64; t += 256) {
            int f = t >> 6, c4 = t & 63;
            xs4[f * 64 + (c4 ^ (f & 7))] = src[t];
        }
        __syncthreads();

        int q = __builtin_amdgcn_readfirstlane(tid >> 6);  // wave-uniform s-quarter
        int fl = tid & 63;
        int f2 = (fl < TF - 64) ? fl + 64 : fl;  // second f-row (clamped; store-masked)
        const float* arow = aT + ((size_t)b * SS + q * 64) * PP;  // uniform -> s_load

        float acc0[PP], acc1[PP];
#pragma unroll
        for (int p = 0; p < PP; ++p) { acc0[p] = 0.f; acc1[p] = 0.f; }

        int cb = q * 16;
        int sw = fl & 7;
        int r0 = fl * 64, r1 = f2 * 64;
#pragma unroll 2
        for (int ii = 0; ii < 16; ++ii) {
            float4 xa = xs4[r0 + ((cb + ii) ^ sw)];
            float4 xb = xs4[r1 + ((cb + ii) ^ sw)];
            const float* ar = arow + ii * 4 * PP;
#pragma unroll
            for (int j = 0; j < 4; ++j) {
                float va = (j == 0) ? xa.x : (j == 1) ? xa.y : (j == 2) ? xa.z : xa.w;
                float vb = (j == 0) ? xb.x : (j == 1) ? xb.y : (j == 2) ? xb.z : xb.w;
                const float* arj = ar + j * PP;
#pragma unroll
                for (int p = 0; p < PP; ++p) {
                    float av = arj[p];
                    acc0[p] = fmaf(av, va, acc0[p]);
                    acc1[p] = fmaf(av, vb, acc1[p]);
                }
            }
        }

        __syncthreads();
        float* part = (float*)smem;  // [2][256][25]
#pragma unroll
        for (int p = 0; p < PP; ++p) {
            part[(0 * 256 + tid) * 25 + p] = acc0[p];
            part[(1 * 256 + tid) * 25 + p] = acc1[p];
        }
        __syncthreads();

        int fl2 = tid & 63, pg = tid >> 6;
#pragma unroll
        for (int j = 0; j < 6; ++j) {
            int p = pg * 6 + j;
            float iv = invd[b * PP + p];
            float v0 = part[(fl2) * 25 + p] + part[(64 + fl2) * 25 + p] +
                       part[(128 + fl2) * 25 + p] + part[(192 + fl2) * 25 + p];
            out[((size_t)b * PP + p) * FF + fbase + fl2] = v0 * iv;
            if (fl2 < TF - 64) {
                float v1 = part[(256 + fl2) * 25 + p] + part[(256 + 64 + fl2) * 25 + p] +
                           part[(256 + 128 + fl2) * 25 + p] + part[(256 + 192 + fl2) * 25 + p];
                out[((size_t)b * PP + p) * FF + fbase + 64 + fl2] = v1 * iv;
            }
        }
    }
}

extern "C" void kernel_launch(void* const* d_in, const int* in_sizes, int n_in,
                              void* d_out, int out_size, void* d_ws, size_t ws_size,
                              hipStream_t stream) {
    const float* xyz1 = (const float*)d_in[0];
    const float* xyz2 = (const float*)d_in[1];
    const float* pts2 = (const float*)d_in[2];
    const float* ps   = (const float*)d_in[3];
    float* out = (float*)d_out;
    float* ws = (float*)d_ws;

    void* kargs[] = {(void*)&xyz1, (void*)&xyz2, (void*)&pts2, (void*)&ps,
                     (void*)&ws, (void*)&out};

    const size_t needPartial =
        (size_t)(128 + BB * SS * PP + GRID * SS * PP + GRID * PP) * sizeof(float);

    if (ws_size >= needPartial) {
        hipFuncSetAttribute((const void*)fused<true>,
                            hipFuncAttributeMaxDynamicSharedMemorySize, LDS_BYTES);
        hipLaunchCooperativeKernel((void*)fused<true>, dim3(GRID), dim3(256),
                                   kargs, LDS_BYTES, stream);
    } else {
        hipFuncSetAttribute((const void*)fused<false>,
                            hipFuncAttributeMaxDynamicSharedMemorySize, LDS_BYTES);
        hipLaunchCooperativeKernel((void*)fused<false>, dim3(GRID), dim3(256),
                                   kargs, LDS_BYTES, stream);
    }
}

// Round 5
// 40.821 us; speedup vs baseline: 3.2703x; 3.2703x over previous
//
#include <hip/hip_runtime.h>
#include <float.h>

#define BB 4
#define NN 2048
#define SS 256
#define FF 7680   // C_FEAT * NA = 128*60
#define PP 24

#define KVPAD(s) ((s) + ((s) >> 5))

// ws layout (floats):
//   [0,128)                      invd[b][p]  (96 used)
//   [128, 128+BB*SS*PP)          A_T[b][s][p]
//   [AOFF, AOFF+NBLK*SS*PP)      partial[blk][s][p]
//   [DOFF, DOFF+NBLK*PP)         dsumP[blk][p]

// branchless insert of (v, vi) into ascending triple, strict < (incumbent wins ties)
#define INSERT3(v, vi)                                                       \
    {                                                                        \
        bool c0 = (v) < t0, c1 = (v) < t1, c2 = (v) < t2;                    \
        float n2 = c1 ? t1 : (c2 ? (v) : t2);                                \
        int m2 = c1 ? j1 : (c2 ? (vi) : j2);                                 \
        float n1 = c0 ? t0 : (c1 ? (v) : t1);                                \
        int m1 = c0 ? j0 : (c1 ? (vi) : j1);                                 \
        t0 = c0 ? (v) : t0;                                                  \
        j0 = c0 ? (vi) : j0;                                                 \
        t1 = n1; j1 = m1; t2 = n2; j2 = m2;                                  \
    }

// merge partner's triple; lower-s-range thread's triple is the base (wins ties)
#define MERGE_ROUND(m)                                                       \
    {                                                                        \
        float q0 = __shfl_xor(t0, (m)), q1 = __shfl_xor(t1, (m)),            \
              q2 = __shfl_xor(t2, (m));                                      \
        int r0 = __shfl_xor(j0, (m)), r1 = __shfl_xor(j1, (m)),              \
            r2 = __shfl_xor(j2, (m));                                        \
        bool lw = ((h & (m)) == 0);                                          \
        float is0 = lw ? q0 : t0, is1 = lw ? q1 : t1, is2 = lw ? q2 : t2;    \
        int ij0 = lw ? r0 : j0, ij1 = lw ? r1 : j1, ij2 = lw ? r2 : j2;      \
        float bs0 = lw ? t0 : q0, bs1 = lw ? t1 : q1, bs2 = lw ? t2 : q2;    \
        int bj0 = lw ? j0 : r0, bj1 = lw ? j1 : r1, bj2 = lw ? j2 : r2;      \
        t0 = bs0; t1 = bs1; t2 = bs2; j0 = bj0; j1 = bj1; j2 = bj2;          \
        INSERT3(is0, ij0);                                                   \
        INSERT3(is1, ij1);                                                   \
        INSERT3(is2, ij2);                                                   \
    }

// ---------------- kernel 2: 3-NN + scatter into per-block partial A + dsum ----------------
// TPN threads per n; block covers NPB=256/TPN n's; each thread scans SS/TPN s's.
template <int TPN, bool ATOMIC_OUT>
__global__ __launch_bounds__(256) void k2_scatter(const float* __restrict__ xyz1,
                                                  const float* __restrict__ xyz2,
                                                  const float* __restrict__ ps,
                                                  float* __restrict__ dst,
                                                  float* __restrict__ dsumOut) {
    constexpr int NPB = 256 / TPN;
    constexpr int CHUNKS = NN / NPB;
    constexpr int SPT = SS / TPN;
    constexpr int PPT = PP / TPN;
    int b = blockIdx.x / CHUNKS;
    int chunk = blockIdx.x % CHUNKS;
    int tid = threadIdx.x;

    __shared__ float4 kv[SS + (SS >> 5)];
    __shared__ float aloc[SS][PP];
    __shared__ float dsum[PP];

    {   // stage sparse coords + |p|^2, bank-swizzled
        int s = tid;
        float x = xyz2[b * 3 * SS + s];
        float y = xyz2[b * 3 * SS + SS + s];
        float z = xyz2[b * 3 * SS + 2 * SS + s];
        kv[KVPAD(s)] = make_float4(x, y, z, x * x + y * y + z * z);
    }
    for (int i = tid; i < SS * PP; i += 256) ((float*)aloc)[i] = 0.f;
    if (tid < PP) dsum[tid] = 0.f;
    __syncthreads();

    int h = tid % TPN;
    int n = chunk * NPB + tid / TPN;
    const float* x1p = xyz1 + ((size_t)b * NN + n) * 3;
    float x = x1p[0], y = x1p[1], z = x1p[2];
    float x1sq = x * x + y * y + z * z;

    float t0 = FLT_MAX, t1 = FLT_MAX, t2 = FLT_MAX;
    int j0 = 0, j1 = 0, j2 = 0;
    int sbeg = h * SPT;
#pragma unroll 4
    for (int s = sbeg; s < sbeg + SPT; ++s) {
        float4 c = kv[KVPAD(s)];
        float dt = x * c.x;
        dt = fmaf(y, c.y, dt);
        dt = fmaf(z, c.z, dt);
        float d = fmaf(-2.f, dt, x1sq + c.w);
        INSERT3(d, s);
    }
#pragma unroll
    for (int m = 1; m < TPN; m <<= 1) { MERGE_ROUND(m); }

    float w0 = 1.f / (t0 + 1e-8f);
    float w1 = 1.f / (t1 + 1e-8f);
    float w2 = 1.f / (t2 + 1e-8f);
    float wsum = w0 + w1 + w2;
    w0 /= wsum; w1 /= wsum; w2 /= wsum;

    // scatter + denom partials: this thread handles PPT of the 24 parts for its n
    const float* prow = ps + ((size_t)b * NN + n) * PP + h * PPT;
#pragma unroll
    for (int j = 0; j < PPT; ++j) {
        float v = prow[j];
        atomicAdd(&dsum[h * PPT + j], fabsf(v));
        atomicAdd(&aloc[j0][h * PPT + j], v * w0);
        atomicAdd(&aloc[j1][h * PPT + j], v * w1);
        atomicAdd(&aloc[j2][h * PPT + j], v * w2);
    }
    __syncthreads();

    if (ATOMIC_OUT) {
        int s = tid;
        float* d2 = dst + ((size_t)b * SS + s) * PP;
#pragma unroll
        for (int p = 0; p < PP; ++p) unsafeAtomicAdd(&d2[p], aloc[s][p]);
        if (tid < PP) unsafeAtomicAdd(&dsumOut[b * PP + tid], dsum[tid]);
    } else {
        float* d2 = dst + (size_t)blockIdx.x * (SS * PP);
        for (int i = tid; i < SS * PP; i += 256) d2[i] = ((float*)aloc)[i];
        if (tid < PP) dsumOut[blockIdx.x * PP + tid] = dsum[tid];
    }
}

// ---------------- kernel 2b: reduce partials -> A_T and dsumP -> invd ----------------
template <int CHUNKS>
__global__ __launch_bounds__(256) void k2b_reduce(const float* __restrict__ partial,
                                                  const float* __restrict__ dsumP,
                                                  float* __restrict__ aT,
                                                  float* __restrict__ invd) {
    int i = blockIdx.x * 256 + threadIdx.x;   // over BB*SS*PP
    int b = i / (SS * PP);
    int sp = i - b * (SS * PP);
    const float* src = partial + ((size_t)b * CHUNKS) * (SS * PP) + sp;
    float acc = 0.f;
#pragma unroll 4
    for (int c = 0; c < CHUNKS; ++c) acc += src[(size_t)c * (SS * PP)];
    aT[i] = acc;

    if (blockIdx.x == 0 && threadIdx.x < BB * PP) {
        int b2 = threadIdx.x / PP, p = threadIdx.x - b2 * PP;
        float s = 0.f;
#pragma unroll 4
        for (int c = 0; c < CHUNKS; ++c) s += dsumP[((size_t)b2 * CHUNKS + c) * PP + p];
        invd[threadIdx.x] = 1.0f / fmaxf(s, 1e-12f);
    }
}

// tiny fixup for the atomic fallback path: denom -> invd in place
__global__ void k2c_invert(float* __restrict__ invd) {
    if (threadIdx.x < BB * PP) {
        float s = invd[threadIdx.x];
        invd[threadIdx.x] = 1.0f / fmaxf(s, 1e-12f);
    }
}

// ---------------- kernel 3: out[b,p,f] = invd[b,p] * sum_s A_T[b,s,p]*pts2[b,f,s] ----------------
// Round-2 version: direct strided float4 loads of pts2 (L2/L3 absorbs), A via
// wave-uniform s_load (aT is const __restrict__, no aliasing stores here).
__global__ __launch_bounds__(256) void k3_contract(const float* __restrict__ pts2,
                                                   const float* __restrict__ aT,
                                                   const float* __restrict__ invd,
                                                   float* __restrict__ out) {
    int bb = blockIdx.x;
    int b = bb / 120;
    int fbase = (bb % 120) * 64;
    int tid = threadIdx.x;
    int q = __builtin_amdgcn_readfirstlane(tid >> 6);  // wave-uniform s-quarter
    int fl = tid & 63;
    int f = fbase + fl;

    const float* prow = pts2 + ((size_t)b * FF + f) * SS + q * 64;
    const float* arow = aT + ((size_t)b * SS + q * 64) * PP;  // uniform -> s_load

    float acc[PP];
#pragma unroll
    for (int p = 0; p < PP; ++p) acc[p] = 0.f;

    for (int i = 0; i < 64; i += 4) {
        float4 pv = *(const float4*)(prow + i);
#pragma unroll
        for (int j = 0; j < 4; ++j) {
            float pj = (j == 0) ? pv.x : (j == 1) ? pv.y : (j == 2) ? pv.z : pv.w;
#pragma unroll
            for (int p = 0; p < PP; ++p)
                acc[p] = fmaf(arow[(i + j) * PP + p], pj, acc[p]);
        }
    }

    __shared__ float part[4][64][25];  // pad 24->25 to break bank conflicts
#pragma unroll
    for (int p = 0; p < PP; ++p) part[q][fl][p] = acc[p];
    __syncthreads();

    int fl2 = tid & 63;
    int pg = tid >> 6;
#pragma unroll
    for (int j = 0; j < 6; ++j) {
        int p = pg * 6 + j;
        float v = part[0][fl2][p] + part[1][fl2][p] + part[2][fl2][p] + part[3][fl2][p];
        v *= invd[b * PP + p];
        out[((size_t)b * PP + p) * FF + fbase + fl2] = v;
    }
}

extern "C" void kernel_launch(void* const* d_in, const int* in_sizes, int n_in,
                              void* d_out, int out_size, void* d_ws, size_t ws_size,
                              hipStream_t stream) {
    const float* xyz1 = (const float*)d_in[0];
    const float* xyz2 = (const float*)d_in[1];
    const float* pts2 = (const float*)d_in[2];
    const float* ps   = (const float*)d_in[3];
    float* out = (float*)d_out;
    float* invd = (float*)d_ws;
    float* aT = (float*)d_ws + 128;
    float* partial = (float*)d_ws + 128 + BB * SS * PP;

    const size_t baseFloats = 128 + (size_t)BB * SS * PP;
    auto need = [&](int nblk) {
        // partials + dsumP
        return (baseFloats + (size_t)nblk * SS * PP + (size_t)nblk * PP) * sizeof(float);
    };

    if (ws_size >= need(BB * 64)) {
        constexpr int NBLK = BB * 64;
        float* dsumP = partial + (size_t)NBLK * SS * PP;
        k2_scatter<8, false><<<NBLK, 256, 0, stream>>>(xyz1, xyz2, ps, partial, dsumP);
        k2b_reduce<64><<<(BB * SS * PP) / 256, 256, 0, stream>>>(partial, dsumP, aT, invd);
    } else if (ws_size >= need(BB * 32)) {
        constexpr int NBLK = BB * 32;
        float* dsumP = partial + (size_t)NBLK * SS * PP;
        k2_scatter<4, false><<<NBLK, 256, 0, stream>>>(xyz1, xyz2, ps, partial, dsumP);
        k2b_reduce<32><<<(BB * SS * PP) / 256, 256, 0, stream>>>(partial, dsumP, aT, invd);
    } else {
        hipMemsetAsync(d_ws, 0, baseFloats * sizeof(float), stream);
        k2_scatter<2, true><<<BB * 16, 256, 0, stream>>>(xyz1, xyz2, ps, aT, invd);
        k2c_invert<<<1, 128, 0, stream>>>(invd);
    }

    k3_contract<<<BB * 120, 256, 0, stream>>>(pts2, aT, invd, out);
}

// Round 6
// 39.468 us; speedup vs baseline: 3.3825x; 1.0343x over previous
//
#include <hip/hip_runtime.h>
#include <float.h>

#define BB 4
#define NN 2048
#define SS 256
#define FF 7680   // C_FEAT * NA = 128*60
#define PP 24

#define KVPAD(s) ((s) + ((s) >> 5))

// ws layout (floats):
//   [0,128)                      invd[b][p]  (96 used)
//   [128, 128+BB*SS*PP)          A_T[b][s][p]
//   then partial[nblk][s][p], then dsumP[nblk][p]

// branchless insert of (v, vi) into ascending triple, strict < (incumbent wins ties)
#define INSERT3(v, vi)                                                       \
    {                                                                        \
        bool c0 = (v) < t0, c1 = (v) < t1, c2 = (v) < t2;                    \
        float n2 = c1 ? t1 : (c2 ? (v) : t2);                                \
        int m2 = c1 ? j1 : (c2 ? (vi) : j2);                                 \
        float n1 = c0 ? t0 : (c1 ? (v) : t1);                                \
        int m1 = c0 ? j0 : (c1 ? (vi) : j1);                                 \
        t0 = c0 ? (v) : t0;                                                  \
        j0 = c0 ? (vi) : j0;                                                 \
        t1 = n1; j1 = m1; t2 = n2; j2 = m2;                                  \
    }

// merge partner's triple; lower-s-range thread's triple is the base (wins ties)
#define MERGE_ROUND(m)                                                       \
    {                                                                        \
        float q0 = __shfl_xor(t0, (m)), q1 = __shfl_xor(t1, (m)),            \
              q2 = __shfl_xor(t2, (m));                                      \
        int r0 = __shfl_xor(j0, (m)), r1 = __shfl_xor(j1, (m)),              \
            r2 = __shfl_xor(j2, (m));                                        \
        bool lw = ((h & (m)) == 0);                                          \
        float is0 = lw ? q0 : t0, is1 = lw ? q1 : t1, is2 = lw ? q2 : t2;    \
        int ij0 = lw ? r0 : j0, ij1 = lw ? r1 : j1, ij2 = lw ? r2 : j2;      \
        float bs0 = lw ? t0 : q0, bs1 = lw ? t1 : q1, bs2 = lw ? t2 : q2;    \
        int bj0 = lw ? j0 : r0, bj1 = lw ? j1 : r1, bj2 = lw ? j2 : r2;      \
        t0 = bs0; t1 = bs1; t2 = bs2; j0 = bj0; j1 = bj1; j2 = bj2;          \
        INSERT3(is0, ij0);                                                   \
        INSERT3(is1, ij1);                                                   \
        INSERT3(is2, ij2);                                                   \
    }

// ---------------- kernel 2: 3-NN + scatter into per-block partial A + dsum ----------------
// TPN threads per n; block covers NPB=256/TPN n's; each thread scans SS/TPN s's.
template <int TPN, bool ATOMIC_OUT>
__global__ __launch_bounds__(256) void k2_scatter(const float* __restrict__ xyz1,
                                                  const float* __restrict__ xyz2,
                                                  const float* __restrict__ ps,
                                                  float* __restrict__ dst,
                                                  float* __restrict__ dsumOut) {
    constexpr int NPB = 256 / TPN;
    constexpr int CHUNKS = NN / NPB;
    constexpr int SPT = SS / TPN;
    constexpr int PPT = PP / TPN;
    int b = blockIdx.x / CHUNKS;
    int chunk = blockIdx.x % CHUNKS;
    int tid = threadIdx.x;

    __shared__ float4 kv[SS + (SS >> 5)];
    __shared__ float aloc[SS][PP];
    __shared__ float dsum[PP];

    {   // stage sparse coords + |p|^2, bank-swizzled
        int s = tid;
        float x = xyz2[b * 3 * SS + s];
        float y = xyz2[b * 3 * SS + SS + s];
        float z = xyz2[b * 3 * SS + 2 * SS + s];
        kv[KVPAD(s)] = make_float4(x, y, z, x * x + y * y + z * z);
    }
    for (int i = tid; i < SS * PP; i += 256) ((float*)aloc)[i] = 0.f;
    if (tid < PP) dsum[tid] = 0.f;
    __syncthreads();

    int h = tid % TPN;
    int n = chunk * NPB + tid / TPN;
    const float* x1p = xyz1 + ((size_t)b * NN + n) * 3;
    float x = x1p[0], y = x1p[1], z = x1p[2];
    float x1sq = x * x + y * y + z * z;

    float t0 = FLT_MAX, t1 = FLT_MAX, t2 = FLT_MAX;
    int j0 = 0, j1 = 0, j2 = 0;
    int sbeg = h * SPT;
#pragma unroll 4
    for (int s = sbeg; s < sbeg + SPT; ++s) {
        float4 c = kv[KVPAD(s)];
        float dt = x * c.x;
        dt = fmaf(y, c.y, dt);
        dt = fmaf(z, c.z, dt);
        float d = fmaf(-2.f, dt, x1sq + c.w);
        INSERT3(d, s);
    }
#pragma unroll
    for (int m = 1; m < TPN; m <<= 1) { MERGE_ROUND(m); }

    float w0 = 1.f / (t0 + 1e-8f);
    float w1 = 1.f / (t1 + 1e-8f);
    float w2 = 1.f / (t2 + 1e-8f);
    float wsum = w0 + w1 + w2;
    w0 /= wsum; w1 /= wsum; w2 /= wsum;

    // scatter + denom partials: this thread handles PPT of the 24 parts for its n
    const float* prow = ps + ((size_t)b * NN + n) * PP + h * PPT;
#pragma unroll
    for (int j = 0; j < PPT; ++j) {
        float v = prow[j];
        atomicAdd(&dsum[h * PPT + j], fabsf(v));
        atomicAdd(&aloc[j0][h * PPT + j], v * w0);
        atomicAdd(&aloc[j1][h * PPT + j], v * w1);
        atomicAdd(&aloc[j2][h * PPT + j], v * w2);
    }
    __syncthreads();

    if (ATOMIC_OUT) {
        int s = tid;
        float* d2 = dst + ((size_t)b * SS + s) * PP;
#pragma unroll
        for (int p = 0; p < PP; ++p) unsafeAtomicAdd(&d2[p], aloc[s][p]);
        if (tid < PP) unsafeAtomicAdd(&dsumOut[b * PP + tid], dsum[tid]);
    } else {
        float* d2 = dst + (size_t)blockIdx.x * (SS * PP);
        for (int i = tid; i < SS * PP; i += 256) d2[i] = ((float*)aloc)[i];
        if (tid < PP) dsumOut[blockIdx.x * PP + tid] = dsum[tid];
    }
}

// ---------------- kernel 2b: reduce partials -> A_T and dsumP -> invd ----------------
template <int CHUNKS>
__global__ __launch_bounds__(256) void k2b_reduce(const float* __restrict__ partial,
                                                  const float* __restrict__ dsumP,
                                                  float* __restrict__ aT,
                                                  float* __restrict__ invd) {
    int i = blockIdx.x * 256 + threadIdx.x;   // over BB*SS*PP
    int b = i / (SS * PP);
    int sp = i - b * (SS * PP);
    const float* src = partial + ((size_t)b * CHUNKS) * (SS * PP) + sp;
    float acc = 0.f;
#pragma unroll 4
    for (int c = 0; c < CHUNKS; ++c) acc += src[(size_t)c * (SS * PP)];
    aT[i] = acc;

    if (blockIdx.x == 0 && threadIdx.x < BB * PP) {
        int b2 = threadIdx.x / PP, p = threadIdx.x - b2 * PP;
        float s = 0.f;
#pragma unroll 4
        for (int c = 0; c < CHUNKS; ++c) s += dsumP[((size_t)b2 * CHUNKS + c) * PP + p];
        invd[threadIdx.x] = 1.0f / fmaxf(s, 1e-12f);
    }
}

// tiny fixup for the atomic fallback path: denom -> invd in place
__global__ void k2c_invert(float* __restrict__ invd) {
    if (threadIdx.x < BB * PP) {
        float s = invd[threadIdx.x];
        invd[threadIdx.x] = 1.0f / fmaxf(s, 1e-12f);
    }
}

// ---------------- kernel 3: out[b,p,f] = invd[b,p] * sum_s A_T[b,s,p]*pts2[b,f,s] ----------------
// Direct strided float4 loads of pts2 (L2/L3 absorbs), A via wave-uniform s_load
// (aT is const __restrict__, no aliasing stores here).
__global__ __launch_bounds__(256) void k3_contract(const float* __restrict__ pts2,
                                                   const float* __restrict__ aT,
                                                   const float* __restrict__ invd,
                                                   float* __restrict__ out) {
    int bb = blockIdx.x;
    int b = bb / 120;
    int fbase = (bb % 120) * 64;
    int tid = threadIdx.x;
    int q = __builtin_amdgcn_readfirstlane(tid >> 6);  // wave-uniform s-quarter
    int fl = tid & 63;
    int f = fbase + fl;

    const float* prow = pts2 + ((size_t)b * FF + f) * SS + q * 64;
    const float* arow = aT + ((size_t)b * SS + q * 64) * PP;  // uniform -> s_load

    float acc[PP];
#pragma unroll
    for (int p = 0; p < PP; ++p) acc[p] = 0.f;

#pragma unroll 4
    for (int i = 0; i < 64; i += 4) {
        float4 pv = *(const float4*)(prow + i);
#pragma unroll
        for (int j = 0; j < 4; ++j) {
            float pj = (j == 0) ? pv.x : (j == 1) ? pv.y : (j == 2) ? pv.z : pv.w;
#pragma unroll
            for (int p = 0; p < PP; ++p)
                acc[p] = fmaf(arow[(i + j) * PP + p], pj, acc[p]);
        }
    }

    __shared__ float part[4][64][25];  // pad 24->25 to break bank conflicts
#pragma unroll
    for (int p = 0; p < PP; ++p) part[q][fl][p] = acc[p];
    __syncthreads();

    int fl2 = tid & 63;
    int pg = tid >> 6;
#pragma unroll
    for (int j = 0; j < 6; ++j) {
        int p = pg * 6 + j;
        float v = part[0][fl2][p] + part[1][fl2][p] + part[2][fl2][p] + part[3][fl2][p];
        v *= invd[b * PP + p];
        out[((size_t)b * PP + p) * FF + fbase + fl2] = v;
    }
}

extern "C" void kernel_launch(void* const* d_in, const int* in_sizes, int n_in,
                              void* d_out, int out_size, void* d_ws, size_t ws_size,
                              hipStream_t stream) {
    const float* xyz1 = (const float*)d_in[0];
    const float* xyz2 = (const float*)d_in[1];
    const float* pts2 = (const float*)d_in[2];
    const float* ps   = (const float*)d_in[3];
    float* out = (float*)d_out;
    float* invd = (float*)d_ws;
    float* aT = (float*)d_ws + 128;
    float* partial = (float*)d_ws + 128 + BB * SS * PP;

    const size_t baseFloats = 128 + (size_t)BB * SS * PP;
    auto need = [&](int nblk) {
        return (baseFloats + (size_t)nblk * SS * PP + (size_t)nblk * PP) * sizeof(float);
    };

    if (ws_size >= need(BB * 32)) {
        constexpr int NBLK = BB * 32;   // TPN=4, CHUNKS=32
        float* dsumP = partial + (size_t)NBLK * SS * PP;
        k2_scatter<4, false><<<NBLK, 256, 0, stream>>>(xyz1, xyz2, ps, partial, dsumP);
        k2b_reduce<32><<<(BB * SS * PP) / 256, 256, 0, stream>>>(partial, dsumP, aT, invd);
    } else if (ws_size >= need(BB * 16)) {
        constexpr int NBLK = BB * 16;   // TPN=2, CHUNKS=16
        float* dsumP = partial + (size_t)NBLK * SS * PP;
        k2_scatter<2, false><<<NBLK, 256, 0, stream>>>(xyz1, xyz2, ps, partial, dsumP);
        k2b_reduce<16><<<(BB * SS * PP) / 256, 256, 0, stream>>>(partial, dsumP, aT, invd);
    } else {
        hipMemsetAsync(d_ws, 0, baseFloats * sizeof(float), stream);
        k2_scatter<2, true><<<BB * 16, 256, 0, stream>>>(xyz1, xyz2, ps, aT, invd);
        k2c_invert<<<1, 128, 0, stream>>>(invd);
    }

    k3_contract<<<BB * 120, 256, 0, stream>>>(pts2, aT, invd, out);
}